// Round 7
// baseline (255.777 us; speedup 1.0000x reference)
//
#include <hip/hip_runtime.h>

#define NUSER 100000
#define NITEM 150000
#define NBRAND 5000
#define NNODES (NUSER + NITEM + NBRAND)   // 255000
#define DIM 64
#define NOUTROWS (NUSER + NITEM)          // 250000

#define BINSHIFT 10
#define NBINS ((NNODES + (1 << BINSHIFT) - 1) >> BINSHIFT)   // 250
#define EPB 4096          // edges per binA block (16 per thread)
#define CAP 12288         // capacity per bin region (expected 8031 +/- 90)

// bf16 helpers (manual, RNE rounding)
__device__ __forceinline__ float bf2f(unsigned short u) {
    union { unsigned int i; float f; } c;
    c.i = ((unsigned int)u) << 16;
    return c.f;
}
__device__ __forceinline__ unsigned short f2bf(float f) {
    union { float f; unsigned int i; } c;
    c.f = f;
    unsigned int r = c.i + 0x7FFFu + ((c.i >> 16) & 1u);
    return (unsigned short)(r >> 16);
}

// ============================ CSR build =====================================
// Phase A: counting sort into 250 fixed-capacity row-bins. Row ids cached in
// registers across the two passes; 16 edges/thread, 489 blocks (~2/CU).
__global__ __launch_bounds__(256) void lgcn_binA(const int* __restrict__ rows,
                                                 const int* __restrict__ cols,
                                                 const float* __restrict__ vals,
                                                 int* __restrict__ binCnt,
                                                 int2* __restrict__ binned,
                                                 int nedges) {
    __shared__ int hist[NBINS];
    __shared__ int base[NBINS];
    for (int i = threadIdx.x; i < NBINS; i += 256) hist[i] = 0;
    __syncthreads();
    int beg = blockIdx.x * EPB;
    int end = beg + EPB;
    if (end > nedges) end = nedges;
    int r[16];
    #pragma unroll
    for (int k = 0; k < 16; ++k) {
        int e = beg + threadIdx.x + k * 256;
        r[k] = (e < end) ? rows[e] : -1;
        if (r[k] >= 0) atomicAdd(&hist[r[k] >> BINSHIFT], 1);
    }
    __syncthreads();
    for (int i = threadIdx.x; i < NBINS; i += 256) {
        int h = hist[i];
        base[i] = h ? (i * CAP + atomicAdd(&binCnt[i], h)) : 0;
        hist[i] = 0;                       // reuse as within-block position
    }
    __syncthreads();
    #pragma unroll
    for (int k = 0; k < 16; ++k) {
        int e = beg + threadIdx.x + k * 256;
        if (r[k] >= 0) {
            int b = r[k] >> BINSHIFT;
            int pos = base[b] + atomicAdd(&hist[b], 1);
            int2 p;
            p.x = ((r[k] & ((1 << BINSHIFT) - 1)) << 18) | cols[e];
            p.y = __float_as_int(vals[e]);
            binned[pos] = p;
        }
    }
}

// Phase B: one block per bin; fused binCnt-scan (gbase computed in-block).
// 1024-row histogram + exclusive scan in LDS, rowptr written directly,
// scatter via LDS cursors into the bin's contiguous colval window.
__global__ __launch_bounds__(256) void lgcn_binB(const int* __restrict__ binCnt,
                                                 const int2* __restrict__ binned,
                                                 int2* __restrict__ colval,
                                                 int* __restrict__ rowptr,
                                                 int nedges) {
    __shared__ int lhist[1024];
    __shared__ int lcur[1024];
    __shared__ int part[256];
    __shared__ int sScan[256];
    int b = blockIdx.x;
    int t = threadIdx.x;
    // inline exclusive scan of the 250 bin counts
    int v = (t < NBINS) ? binCnt[t] : 0;
    sScan[t] = v;
    #pragma unroll
    for (int k = 0; k < 4; ++k) lhist[t + 256 * k] = 0;
    __syncthreads();
    for (int off = 1; off < 256; off <<= 1) {
        int s2 = (t >= off) ? sScan[t - off] : 0;
        __syncthreads();
        sScan[t] += s2;
        __syncthreads();
    }
    int cnt = binCnt[b];
    int gbase = sScan[b] - cnt;            // exclusive prefix for bin b
    if (b == 0 && t == 0) rowptr[NNODES] = nedges;
    int rbeg = b << BINSHIFT;
    int nrows = NNODES - rbeg;
    if (nrows > 1024) nrows = 1024;
    const int2* bsrc = binned + (size_t)b * CAP;
    for (int e = t; e < cnt; e += 256) {
        atomicAdd(&lhist[bsrc[e].x >> 18], 1);
    }
    __syncthreads();
    int h0 = lhist[4 * t + 0];
    int h1 = lhist[4 * t + 1];
    int h2 = lhist[4 * t + 2];
    int h3 = lhist[4 * t + 3];
    int tot = h0 + h1 + h2 + h3;
    part[t] = tot;
    __syncthreads();
    for (int off = 1; off < 256; off <<= 1) {
        int v2 = (t >= off) ? part[t - off] : 0;
        __syncthreads();
        part[t] += v2;
        __syncthreads();
    }
    int c0 = gbase + part[t] - tot;
    int c1 = c0 + h0;
    int c2 = c1 + h1;
    int c3 = c2 + h2;
    lcur[4 * t + 0] = c0;
    lcur[4 * t + 1] = c1;
    lcur[4 * t + 2] = c2;
    lcur[4 * t + 3] = c3;
    if (4 * t + 0 < nrows) rowptr[rbeg + 4 * t + 0] = c0;
    if (4 * t + 1 < nrows) rowptr[rbeg + 4 * t + 1] = c1;
    if (4 * t + 2 < nrows) rowptr[rbeg + 4 * t + 2] = c2;
    if (4 * t + 3 < nrows) rowptr[rbeg + 4 * t + 3] = c3;
    __syncthreads();
    for (int e = t; e < cnt; e += 256) {
        int2 p = bsrc[e];
        int lr = p.x >> 18;
        int pos = atomicAdd(&lcur[lr], 1);
        int2 cv;
        cv.x = p.x & 0x3FFFF;
        cv.y = p.y;
        colval[pos] = cv;
    }
}

// ============================ init / spmm ===================================

// convert f32 inputs -> bf16 x0 (row-major [NNODES][64])
__global__ __launch_bounds__(256) void lgcn_init(const float4* __restrict__ u,
                                                 const float4* __restrict__ it,
                                                 const float4* __restrict__ br,
                                                 ushort4* __restrict__ x0b) {
    int i = blockIdx.x * blockDim.x + threadIdx.x;
    const int total = NNODES * (DIM / 4);
    if (i >= total) return;
    float4 v;
    if (i < NUSER * (DIM / 4)) {
        v = u[i];
    } else if (i < (NUSER + NITEM) * (DIM / 4)) {
        v = it[i - NUSER * (DIM / 4)];
    } else {
        v = br[i - (NUSER + NITEM) * (DIM / 4)];
    }
    ushort4 o;
    o.x = f2bf(v.x); o.y = f2bf(v.y); o.z = f2bf(v.z); o.w = f2bf(v.w);
    x0b[i] = o;
}

// CSR SpMM over bf16 state. 16 lanes per row, lane handles 4 contiguous dims.
// 8-deep gather pipeline. Non-final: write y (bf16). FINAL: out =
// (x0b + y1 + y2 + s) * 0.25 (f32), user+item rows only.
template <bool FINAL>
__global__ __launch_bounds__(256) void lgcn_spmm_csr(const int* __restrict__ row_ptr,
                                                     const int2* __restrict__ colval,
                                                     const ushort4* __restrict__ xb,
                                                     ushort4* __restrict__ yb,
                                                     const ushort4* __restrict__ x0b,
                                                     const ushort4* __restrict__ y1b,
                                                     const ushort4* __restrict__ y2b,
                                                     float4* __restrict__ out) {
    int t = blockIdx.x * blockDim.x + threadIdx.x;
    int row = t >> 4;
    int l = t & 15;
    if (FINAL) { if (row >= NOUTROWS) return; }
    else       { if (row >= NNODES) return; }
    int beg = row_ptr[row];
    int end = row_ptr[row + 1];
    float4 s = make_float4(0.f, 0.f, 0.f, 0.f);
    int p = beg;
    while (p + 8 <= end) {
        int2 cv[8];
        ushort4 a[8];
        #pragma unroll
        for (int k = 0; k < 8; ++k) cv[k] = colval[p + k];
        #pragma unroll
        for (int k = 0; k < 8; ++k) a[k] = xb[(size_t)cv[k].x * (DIM / 4) + l];
        #pragma unroll
        for (int k = 0; k < 8; ++k) {
            float v = __int_as_float(cv[k].y);
            s.x += v * bf2f(a[k].x); s.y += v * bf2f(a[k].y);
            s.z += v * bf2f(a[k].z); s.w += v * bf2f(a[k].w);
        }
        p += 8;
    }
    if (p + 4 <= end) {
        int2 cv[4];
        ushort4 a[4];
        #pragma unroll
        for (int k = 0; k < 4; ++k) cv[k] = colval[p + k];
        #pragma unroll
        for (int k = 0; k < 4; ++k) a[k] = xb[(size_t)cv[k].x * (DIM / 4) + l];
        #pragma unroll
        for (int k = 0; k < 4; ++k) {
            float v = __int_as_float(cv[k].y);
            s.x += v * bf2f(a[k].x); s.y += v * bf2f(a[k].y);
            s.z += v * bf2f(a[k].z); s.w += v * bf2f(a[k].w);
        }
        p += 4;
    }
    if (p + 2 <= end) {
        int2 cv0 = colval[p];
        int2 cv1 = colval[p + 1];
        ushort4 a0 = xb[(size_t)cv0.x * (DIM / 4) + l];
        ushort4 a1 = xb[(size_t)cv1.x * (DIM / 4) + l];
        float v0 = __int_as_float(cv0.y);
        float v1 = __int_as_float(cv1.y);
        s.x += v0 * bf2f(a0.x); s.y += v0 * bf2f(a0.y);
        s.z += v0 * bf2f(a0.z); s.w += v0 * bf2f(a0.w);
        s.x += v1 * bf2f(a1.x); s.y += v1 * bf2f(a1.y);
        s.z += v1 * bf2f(a1.z); s.w += v1 * bf2f(a1.w);
        p += 2;
    }
    if (p < end) {
        int2 cv = colval[p];
        ushort4 a = xb[(size_t)cv.x * (DIM / 4) + l];
        float v = __int_as_float(cv.y);
        s.x += v * bf2f(a.x); s.y += v * bf2f(a.y);
        s.z += v * bf2f(a.z); s.w += v * bf2f(a.w);
    }
    size_t off = (size_t)row * (DIM / 4) + l;
    if (!FINAL) {
        ushort4 o;
        o.x = f2bf(s.x); o.y = f2bf(s.y); o.z = f2bf(s.z); o.w = f2bf(s.w);
        yb[off] = o;
    } else {
        ushort4 x0 = x0b[off];
        ushort4 a1 = y1b[off];
        ushort4 a2 = y2b[off];
        float4 r;
        r.x = (bf2f(x0.x) + bf2f(a1.x) + bf2f(a2.x) + s.x) * 0.25f;
        r.y = (bf2f(x0.y) + bf2f(a1.y) + bf2f(a2.y) + s.y) * 0.25f;
        r.z = (bf2f(x0.z) + bf2f(a1.z) + bf2f(a2.z) + s.z) * 0.25f;
        r.w = (bf2f(x0.w) + bf2f(a1.w) + bf2f(a2.w) + s.w) * 0.25f;
        out[off] = r;
    }
}

// ============================ launch ========================================

static inline size_t align256(size_t x) { return (x + 255) & ~(size_t)255; }

extern "C" void kernel_launch(void* const* d_in, const int* in_sizes, int n_in,
                              void* d_out, int out_size, void* d_ws, size_t ws_size,
                              hipStream_t stream) {
    const float4* u  = (const float4*)d_in[0];
    const float4* it = (const float4*)d_in[1];
    const float4* br = (const float4*)d_in[2];
    const int*   rows = (const int*)d_in[3];
    const int*   cols = (const int*)d_in[4];
    const float* vals = (const float*)d_in[5];
    const int nedges = in_sizes[3];
    float4* out = (float4*)d_out;

    // workspace layout
    char* ws = (char*)d_ws;
    size_t o = 0;
    ushort4* x0b   = (ushort4*)(ws + o); o = align256(o + (size_t)NNODES * DIM * 2);
    ushort4* y1b   = (ushort4*)(ws + o); o = align256(o + (size_t)NNODES * DIM * 2);
    ushort4* y2b   = (ushort4*)(ws + o); o = align256(o + (size_t)NNODES * DIM * 2);
    int*   rowptr  = (int*)(ws + o);     o = align256(o + (size_t)(NNODES + 1) * 4);
    int*   binCnt  = (int*)(ws + o);     o = align256(o + 256 * 4);
    int2*  colval  = (int2*)(ws + o);    o = align256(o + (size_t)nedges * 8);

    // binned intermediate aliases y1b (dead until spmm1; stream-ordered)
    // size: NBINS * CAP * 8 B = 24.6 MB < 32.6 MB of y1b
    int2* binned = (int2*)y1b;

    const int THREADS = 256;
    const int vecTotal = NNODES * (DIM / 4);
    const int vecBlocks = (vecTotal + THREADS - 1) / THREADS;
    const int spmmBlocks = (NNODES * 16 + THREADS - 1) / THREADS;
    const int finalBlocks = (NOUTROWS * 16 + THREADS - 1) / THREADS;
    const int binABlocks = (nedges + EPB - 1) / EPB;

    // --- CSR build ---
    hipMemsetAsync(binCnt, 0, 256 * 4, stream);
    lgcn_binA<<<binABlocks, THREADS, 0, stream>>>(rows, cols, vals, binCnt, binned, nedges);
    lgcn_binB<<<NBINS, THREADS, 0, stream>>>(binCnt, binned, colval, rowptr, nedges);

    // --- init: f32 inputs -> bf16 x0 ---
    lgcn_init<<<vecBlocks, THREADS, 0, stream>>>(u, it, br, x0b);

    // --- 3 propagation layers ---
    lgcn_spmm_csr<false><<<spmmBlocks, THREADS, 0, stream>>>(rowptr, colval, x0b, y1b,
                                                             nullptr, nullptr, nullptr, nullptr);
    lgcn_spmm_csr<false><<<spmmBlocks, THREADS, 0, stream>>>(rowptr, colval, y1b, y2b,
                                                             nullptr, nullptr, nullptr, nullptr);
    lgcn_spmm_csr<true><<<finalBlocks, THREADS, 0, stream>>>(rowptr, colval, y2b, nullptr,
                                                             x0b, y1b, y2b, out);
}